// Round 4
// baseline (473.876 us; speedup 1.0000x reference)
//
#include <hip/hip_runtime.h>

typedef __bf16 bf16x8 __attribute__((ext_vector_type(8)));
typedef __bf16 bf16x4 __attribute__((ext_vector_type(4)));
typedef float  f32x4  __attribute__((ext_vector_type(4)));

#define LDS_XO 0        // x (bf16, [128][128]) then attn-out O [n][c]
#define LDS_Q  32768    // q [n][j] bf16
#define LDS_K  65536    // k [m][j] bf16
#define LDS_VT 98304    // v^T [d][m] bf16
#define LDS_P  131072   // per-wave P half-buffer: 2KB x 8 waves
#define LDS_TOTAL 147456

// XOR swizzle for 256B-row tiles.
__device__ __forceinline__ int swz(int row, int colb) {
    return row * 256 + (colb ^ ((row & 7) << 4));
}
// XOR swizzle for 128B-row tiles (P half-buffer). XOR bits 4..6 stay in-row.
__device__ __forceinline__ int pswz(int row, int colb) {
    return row * 128 + (colb ^ ((row & 7) << 4));
}

__global__ void prep_weights(const float* __restrict__ qkv_w,
                             const float* __restrict__ proj_w,
                             __bf16* __restrict__ wq, __bf16* __restrict__ wp) {
    int i = blockIdx.x * 256 + threadIdx.x;           // grid covers 49152
    wq[i] = (__bf16)qkv_w[i];
    if (i < 16384) wp[i] = (__bf16)proj_w[i];
}

__global__ void __launch_bounds__(512, 2)
attn_fused(const float* __restrict__ x, const float* __restrict__ mask,
           const float* __restrict__ qkv_b, const float* __restrict__ proj_b,
           const __bf16* __restrict__ wq, const __bf16* __restrict__ wp,
           float* __restrict__ out) {
    extern __shared__ char smem[];
    const int b    = blockIdx.x;
    const int tid  = threadIdx.x;
    const int wave = tid >> 6;    // 0..7
    const int lane = tid & 63;
    const int l16  = lane & 15;
    const int lg   = lane >> 4;   // 0..3

    // ---------------- Phase A: x -> bf16 LDS (swizzled) ----------------
    {
        const float* xb = x + (size_t)b * 16384;
        #pragma unroll
        for (int it = 0; it < 4; ++it) {
            int i   = it * 512 + tid;
            int row = i >> 4;
            int c8  = (i & 15) << 3;
            float4 f0 = *(const float4*)(xb + row * 128 + c8);
            float4 f1 = *(const float4*)(xb + row * 128 + c8 + 4);
            bf16x8 v;
            v[0] = (__bf16)f0.x; v[1] = (__bf16)f0.y; v[2] = (__bf16)f0.z; v[3] = (__bf16)f0.w;
            v[4] = (__bf16)f1.x; v[5] = (__bf16)f1.y; v[6] = (__bf16)f1.z; v[7] = (__bf16)f1.w;
            *(bf16x8*)(smem + LDS_XO + swz(row, c8 * 2)) = v;
        }
    }
    __syncthreads();

    // ---------------- Phase B: QKV^T = W @ x^T  (swapped operands) -----
    // D[j][n]: lane holds 4 consecutive j (features) at fixed n.
    const int j0 = wave * 48;     // 8 waves x 48 features = 384
    #pragma unroll
    for (int pass = 0; pass < 2; ++pass) {
        f32x4 acc[3][4];
        #pragma unroll
        for (int jt = 0; jt < 3; ++jt)
            #pragma unroll
            for (int nt = 0; nt < 4; ++nt)
                acc[jt][nt] = {0.f, 0.f, 0.f, 0.f};
        #pragma unroll
        for (int kc = 0; kc < 4; ++kc) {
            bf16x8 afr[3];
            #pragma unroll
            for (int jt = 0; jt < 3; ++jt)
                afr[jt] = *(const bf16x8*)(wq + (j0 + jt * 16 + l16) * 128 + kc * 32 + lg * 8);
            bf16x8 bfr[4];
            #pragma unroll
            for (int nt = 0; nt < 4; ++nt)
                bfr[nt] = *(const bf16x8*)(smem + LDS_XO +
                            swz((pass * 4 + nt) * 16 + l16, (kc * 32 + lg * 8) * 2));
            #pragma unroll
            for (int jt = 0; jt < 3; ++jt)
                #pragma unroll
                for (int nt = 0; nt < 4; ++nt)
                    acc[jt][nt] = __builtin_amdgcn_mfma_f32_16x16x32_bf16(
                                      afr[jt], bfr[nt], acc[jt][nt], 0, 0, 0);
        }
        // epilogue: +bias, write q/k as bf16x4 rows, v into v^T layout
        #pragma unroll
        for (int jt = 0; jt < 3; ++jt) {
            int jbase = j0 + jt * 16 + lg * 4;
            float4 bias = *(const float4*)(qkv_b + jbase);
            #pragma unroll
            for (int nt = 0; nt < 4; ++nt) {
                int n = (pass * 4 + nt) * 16 + l16;
                f32x4 a = acc[jt][nt];
                __bf16 e0 = (__bf16)(a[0] + bias.x);
                __bf16 e1 = (__bf16)(a[1] + bias.y);
                __bf16 e2 = (__bf16)(a[2] + bias.z);
                __bf16 e3 = (__bf16)(a[3] + bias.w);
                if (jbase < 128) {
                    bf16x4 v4 = {e0, e1, e2, e3};
                    *(bf16x4*)(smem + LDS_Q + swz(n, jbase * 2)) = v4;
                } else if (jbase < 256) {
                    bf16x4 v4 = {e0, e1, e2, e3};
                    *(bf16x4*)(smem + LDS_K + swz(n, (jbase - 128) * 2)) = v4;
                } else {
                    int d = jbase - 256;
                    *(__bf16*)(smem + LDS_VT + swz(d + 0, n * 2)) = e0;
                    *(__bf16*)(smem + LDS_VT + swz(d + 1, n * 2)) = e1;
                    *(__bf16*)(smem + LDS_VT + swz(d + 2, n * 2)) = e2;
                    *(__bf16*)(smem + LDS_VT + swz(d + 3, n * 2)) = e3;
                }
            }
        }
    }
    __syncthreads();

    // ---------------- Phase C: one (head, row-half) per wave ------------
    const int h  = wave >> 1;     // head 0..3
    const int rh = wave & 1;      // row half: nt in [rh*4, rh*4+4)
    const float sc = 0.17677669529663687f;   // 1/sqrt(32)
    bf16x8 kfr[8];
    #pragma unroll
    for (int mt = 0; mt < 8; ++mt)
        kfr[mt] = *(const bf16x8*)(smem + LDS_K + swz(mt * 16 + l16, (h * 32 + lg * 8) * 2));
    bf16x8 vfr[2][4];
    #pragma unroll
    for (int dt = 0; dt < 2; ++dt)
        #pragma unroll
        for (int kc = 0; kc < 4; ++kc)
            vfr[dt][kc] = *(const bf16x8*)(smem + LDS_VT +
                            swz(h * 32 + dt * 16 + l16, (kc * 32 + lg * 8) * 2));

    const float* mwin = mask + (size_t)(b & 63) * 16384;
    char* pbase = smem + LDS_P + wave * 2048;

    #pragma unroll
    for (int i = 0; i < 4; ++i) {
        const int nt = rh * 4 + i;
        bf16x8 qfr = *(const bf16x8*)(smem + LDS_Q + swz(nt * 16 + l16, (h * 32 + lg * 8) * 2));
        f32x4 s[8];
        #pragma unroll
        for (int mt = 0; mt < 8; ++mt) {
            f32x4 z = {0.f, 0.f, 0.f, 0.f};
            s[mt] = __builtin_amdgcn_mfma_f32_16x16x32_bf16(qfr, kfr[mt], z, 0, 0, 0);
        }
        // scale + mask + row max
        float mx[4] = {-1e30f, -1e30f, -1e30f, -1e30f};
        #pragma unroll
        for (int mt = 0; mt < 8; ++mt)
            #pragma unroll
            for (int r = 0; r < 4; ++r) {
                float v = s[mt][r] * sc + mwin[(nt * 16 + lg * 4 + r) * 128 + mt * 16 + l16];
                s[mt][r] = v;
                mx[r] = fmaxf(mx[r], v);
            }
        #pragma unroll
        for (int r = 0; r < 4; ++r) {
            float m = mx[r];
            m = fmaxf(m, __shfl_xor(m, 1));
            m = fmaxf(m, __shfl_xor(m, 2));
            m = fmaxf(m, __shfl_xor(m, 4));
            m = fmaxf(m, __shfl_xor(m, 8));
            mx[r] = m;
        }
        float sm[4] = {0.f, 0.f, 0.f, 0.f};
        #pragma unroll
        for (int mt = 0; mt < 8; ++mt)
            #pragma unroll
            for (int r = 0; r < 4; ++r) {
                float p = __expf(s[mt][r] - mx[r]);
                s[mt][r] = p;
                sm[r] += p;
            }
        #pragma unroll
        for (int r = 0; r < 4; ++r) {
            float t = sm[r];
            t += __shfl_xor(t, 1);
            t += __shfl_xor(t, 2);
            t += __shfl_xor(t, 4);
            t += __shfl_xor(t, 8);
            sm[r] = 1.f / t;
        }
        // P -> per-wave 2KB LDS in two half-passes (same-wave LDS pipe is
        // in-order, so write->read->overwrite needs no barrier).
        f32x4 o[2];
        o[0] = {0.f, 0.f, 0.f, 0.f};
        o[1] = {0.f, 0.f, 0.f, 0.f};
        #pragma unroll
        for (int hp = 0; hp < 2; ++hp) {
            #pragma unroll
            for (int mtl = 0; mtl < 4; ++mtl) {
                int mt = hp * 4 + mtl;
                #pragma unroll
                for (int r = 0; r < 4; ++r)
                    *(__bf16*)(pbase + pswz(lg * 4 + r, (mtl * 16 + l16) * 2)) =
                        (__bf16)(s[mt][r] * sm[r]);
            }
            #pragma unroll
            for (int q = 0; q < 2; ++q) {
                int kc = hp * 2 + q;
                bf16x8 pafr = *(const bf16x8*)(pbase + pswz(l16, (q * 32 + lg * 8) * 2));
                #pragma unroll
                for (int dt = 0; dt < 2; ++dt)
                    o[dt] = __builtin_amdgcn_mfma_f32_16x16x32_bf16(
                                pafr, vfr[dt][kc], o[dt], 0, 0, 0);
            }
        }
        #pragma unroll
        for (int dt = 0; dt < 2; ++dt)
            #pragma unroll
            for (int r = 0; r < 4; ++r)
                *(__bf16*)(smem + LDS_XO +
                    swz(nt * 16 + lg * 4 + r, (h * 32 + dt * 16 + l16) * 2)) = (__bf16)o[dt][r];
    }
    __syncthreads();

    // ---------------- Phase D: output projection -----------------------
    f32x4 facc[8];
    #pragma unroll
    for (int ct = 0; ct < 8; ++ct)
        facc[ct] = {0.f, 0.f, 0.f, 0.f};
    #pragma unroll
    for (int kc = 0; kc < 4; ++kc) {
        bf16x8 afr = *(const bf16x8*)(smem + LDS_XO +
                        swz(wave * 16 + l16, (kc * 32 + lg * 8) * 2));
        bf16x8 bfr[8];
        #pragma unroll
        for (int ct = 0; ct < 8; ++ct)
            bfr[ct] = *(const bf16x8*)(wp + (ct * 16 + l16) * 128 + kc * 32 + lg * 8);
        #pragma unroll
        for (int ct = 0; ct < 8; ++ct)
            facc[ct] = __builtin_amdgcn_mfma_f32_16x16x32_bf16(
                           afr, bfr[ct], facc[ct], 0, 0, 0);
    }
    float* ob = out + (size_t)b * 16384;
    #pragma unroll
    for (int ct = 0; ct < 8; ++ct) {
        float pb = proj_b[ct * 16 + l16];
        int n0 = wave * 16 + lg * 4;
        #pragma unroll
        for (int r = 0; r < 4; ++r)
            ob[(n0 + r) * 128 + ct * 16 + l16] = facc[ct][r] + pb;
    }
}

extern "C" void kernel_launch(void* const* d_in, const int* in_sizes, int n_in,
                              void* d_out, int out_size, void* d_ws, size_t ws_size,
                              hipStream_t stream) {
    const float* x      = (const float*)d_in[0];
    const float* mask   = (const float*)d_in[1];
    const float* qkv_w  = (const float*)d_in[2];
    const float* qkv_b  = (const float*)d_in[3];
    const float* proj_w = (const float*)d_in[4];
    const float* proj_b = (const float*)d_in[5];
    float* out = (float*)d_out;

    __bf16* wq = (__bf16*)d_ws;            // 384*128 bf16
    __bf16* wp = wq + 49152;               // 128*128 bf16

    prep_weights<<<192, 256, 0, stream>>>(qkv_w, proj_w, wq, wp);

    hipFuncSetAttribute((const void*)attn_fused,
                        hipFuncAttributeMaxDynamicSharedMemorySize, LDS_TOTAL);
    attn_fused<<<2048, 512, LDS_TOTAL, stream>>>(x, mask, qkv_b, proj_b, wq, wp, out);
}

// Round 5
// 408.461 us; speedup vs baseline: 1.1602x; 1.1602x over previous
//
#include <hip/hip_runtime.h>

typedef __bf16 bf16x8 __attribute__((ext_vector_type(8)));
typedef __bf16 bf16x4 __attribute__((ext_vector_type(4)));
typedef float  f32x4  __attribute__((ext_vector_type(4)));

// XOR swizzle for 256B-row tiles.
__device__ __forceinline__ int swz(int row, int colb) {
    return row * 256 + (colb ^ ((row & 7) << 4));
}
// XOR swizzle for 128B-row tiles.
__device__ __forceinline__ int pswz(int row, int colb) {
    return row * 128 + (colb ^ ((row & 7) << 4));
}

__global__ void prep_weights(const float* __restrict__ qkv_w,
                             const float* __restrict__ proj_w,
                             __bf16* __restrict__ wq, __bf16* __restrict__ wp) {
    int i = blockIdx.x * 256 + threadIdx.x;           // grid covers 49152
    wq[i] = (__bf16)qkv_w[i];
    if (i < 16384) wp[i] = (__bf16)proj_w[i];
}

// ================= split path: (window, head-pair) blocks =================
// LDS = 81920 B exactly -> 2 independent blocks per CU (decorrelated stalls).
#define A_LDS_X   0        // x [128][128] bf16, 256B rows -- dead after Phase B
#define A_LDS_P   0        // P: 4 waves x 2KB, overlays x in Phase C
#define A_LDS_Q   32768    // q [128n][64j] bf16, 128B rows
#define A_LDS_K   49152    // k [128m][64j] bf16, 128B rows
#define A_LDS_VT  65536    // vT [64d][128m] bf16, 256B rows
#define A_LDS_TOTAL 81920

__global__ void __launch_bounds__(256, 2)
attn_split(const float* __restrict__ x, const float* __restrict__ mask,
           const float* __restrict__ qkv_b,
           const __bf16* __restrict__ wq,
           __bf16* __restrict__ Og) {
    extern __shared__ char smem[];
    const int b    = blockIdx.x >> 1;   // window
    const int hp   = blockIdx.x & 1;    // head pair: heads {2hp, 2hp+1}
    const int tid  = threadIdx.x;
    const int wave = tid >> 6;          // 0..3
    const int lane = tid & 63;
    const int l16  = lane & 15;
    const int lg   = lane >> 4;         // 0..3

    // ---------------- Phase A: x -> bf16 LDS (swizzled) ----------------
    {
        const float* xb = x + (size_t)b * 16384;
        #pragma unroll
        for (int it = 0; it < 8; ++it) {
            int i   = it * 256 + tid;
            int row = i >> 4;
            int c8  = (i & 15) << 3;
            float4 f0 = *(const float4*)(xb + row * 128 + c8);
            float4 f1 = *(const float4*)(xb + row * 128 + c8 + 4);
            bf16x8 v;
            v[0] = (__bf16)f0.x; v[1] = (__bf16)f0.y; v[2] = (__bf16)f0.z; v[3] = (__bf16)f0.w;
            v[4] = (__bf16)f1.x; v[5] = (__bf16)f1.y; v[6] = (__bf16)f1.z; v[7] = (__bf16)f1.w;
            *(bf16x8*)(smem + A_LDS_X + swz(row, c8 * 2)) = v;
        }
    }
    __syncthreads();

    // ------- Phase B: this head-pair's qkv features = W @ x^T ----------
    // wave handles local features f0..f0+47; local f -> global wq row jg:
    //   f in [0,64)    -> q: jg = hp*64 + f
    //   f in [64,128)  -> k: jg = 128 + hp*64 + (f-64)
    //   f in [128,192) -> v: jg = 256 + hp*64 + (f-128)
    const int f0 = wave * 48;
    #pragma unroll
    for (int pass = 0; pass < 2; ++pass) {
        f32x4 acc[3][4];
        #pragma unroll
        for (int jt = 0; jt < 3; ++jt)
            #pragma unroll
            for (int nt = 0; nt < 4; ++nt)
                acc[jt][nt] = {0.f, 0.f, 0.f, 0.f};
        int jg_t[3];
        #pragma unroll
        for (int jt = 0; jt < 3; ++jt) {
            int ft = f0 + jt * 16;
            jg_t[jt] = (ft < 64) ? (hp * 64 + ft)
                     : (ft < 128) ? (128 + hp * 64 + (ft - 64))
                                  : (256 + hp * 64 + (ft - 128));
        }
        #pragma unroll
        for (int kc = 0; kc < 4; ++kc) {
            bf16x8 afr[3];
            #pragma unroll
            for (int jt = 0; jt < 3; ++jt)
                afr[jt] = *(const bf16x8*)(wq + (jg_t[jt] + l16) * 128 + kc * 32 + lg * 8);
            bf16x8 bfr[4];
            #pragma unroll
            for (int nt = 0; nt < 4; ++nt)
                bfr[nt] = *(const bf16x8*)(smem + A_LDS_X +
                            swz((pass * 4 + nt) * 16 + l16, (kc * 32 + lg * 8) * 2));
            #pragma unroll
            for (int jt = 0; jt < 3; ++jt)
                #pragma unroll
                for (int nt = 0; nt < 4; ++nt)
                    acc[jt][nt] = __builtin_amdgcn_mfma_f32_16x16x32_bf16(
                                      afr[jt], bfr[nt], acc[jt][nt], 0, 0, 0);
        }
        #pragma unroll
        for (int jt = 0; jt < 3; ++jt) {
            int ft = f0 + jt * 16;
            int f  = ft + lg * 4;                 // lane's 4 local features f..f+3
            float4 bias = *(const float4*)(qkv_b + jg_t[jt] + lg * 4);
            #pragma unroll
            for (int nt = 0; nt < 4; ++nt) {
                int n = (pass * 4 + nt) * 16 + l16;
                f32x4 a = acc[jt][nt];
                __bf16 e0 = (__bf16)(a[0] + bias.x);
                __bf16 e1 = (__bf16)(a[1] + bias.y);
                __bf16 e2 = (__bf16)(a[2] + bias.z);
                __bf16 e3 = (__bf16)(a[3] + bias.w);
                if (f < 64) {
                    bf16x4 v4 = {e0, e1, e2, e3};
                    *(bf16x4*)(smem + A_LDS_Q + pswz(n, f * 2)) = v4;
                } else if (f < 128) {
                    bf16x4 v4 = {e0, e1, e2, e3};
                    *(bf16x4*)(smem + A_LDS_K + pswz(n, (f - 64) * 2)) = v4;
                } else {
                    int d = f - 128;
                    *(__bf16*)(smem + A_LDS_VT + swz(d + 0, n * 2)) = e0;
                    *(__bf16*)(smem + A_LDS_VT + swz(d + 1, n * 2)) = e1;
                    *(__bf16*)(smem + A_LDS_VT + swz(d + 2, n * 2)) = e2;
                    *(__bf16*)(smem + A_LDS_VT + swz(d + 3, n * 2)) = e3;
                }
            }
        }
    }
    __syncthreads();   // x now dead; P buffers may overlay it

    // ------- Phase C: wave = (local head, row half); 4 nt iters --------
    const int hl = wave >> 1;           // local head 0/1
    const int rh = wave & 1;
    const int hgl = hp * 2 + hl;        // global head 0..3
    const float sc = 0.17677669529663687f;   // 1/sqrt(32)
    bf16x8 kfr[8];
    #pragma unroll
    for (int mt = 0; mt < 8; ++mt)
        kfr[mt] = *(const bf16x8*)(smem + A_LDS_K +
                      pswz(mt * 16 + l16, (hl * 32 + lg * 8) * 2));
    bf16x8 vfr[2][4];
    #pragma unroll
    for (int dt = 0; dt < 2; ++dt)
        #pragma unroll
        for (int kc = 0; kc < 4; ++kc)
            vfr[dt][kc] = *(const bf16x8*)(smem + A_LDS_VT +
                            swz(hl * 32 + dt * 16 + l16, (kc * 32 + lg * 8) * 2));

    const float* mwin = mask + (size_t)(b & 63) * 16384;
    char* pbase = smem + A_LDS_P + wave * 2048;

    #pragma unroll
    for (int i = 0; i < 4; ++i) {
        const int nt = rh * 4 + i;
        bf16x8 qfr = *(const bf16x8*)(smem + A_LDS_Q +
                        pswz(nt * 16 + l16, (hl * 32 + lg * 8) * 2));
        f32x4 s[8];
        #pragma unroll
        for (int mt = 0; mt < 8; ++mt) {
            f32x4 z = {0.f, 0.f, 0.f, 0.f};
            s[mt] = __builtin_amdgcn_mfma_f32_16x16x32_bf16(qfr, kfr[mt], z, 0, 0, 0);
        }
        float mx[4] = {-1e30f, -1e30f, -1e30f, -1e30f};
        #pragma unroll
        for (int mt = 0; mt < 8; ++mt)
            #pragma unroll
            for (int r = 0; r < 4; ++r) {
                float v = s[mt][r] * sc + mwin[(nt * 16 + lg * 4 + r) * 128 + mt * 16 + l16];
                s[mt][r] = v;
                mx[r] = fmaxf(mx[r], v);
            }
        #pragma unroll
        for (int r = 0; r < 4; ++r) {
            float m = mx[r];
            m = fmaxf(m, __shfl_xor(m, 1));
            m = fmaxf(m, __shfl_xor(m, 2));
            m = fmaxf(m, __shfl_xor(m, 4));
            m = fmaxf(m, __shfl_xor(m, 8));
            mx[r] = m;
        }
        float sm[4] = {0.f, 0.f, 0.f, 0.f};
        #pragma unroll
        for (int mt = 0; mt < 8; ++mt)
            #pragma unroll
            for (int r = 0; r < 4; ++r) {
                float p = __expf(s[mt][r] - mx[r]);
                s[mt][r] = p;
                sm[r] += p;
            }
        #pragma unroll
        for (int r = 0; r < 4; ++r) {
            float t = sm[r];
            t += __shfl_xor(t, 1);
            t += __shfl_xor(t, 2);
            t += __shfl_xor(t, 4);
            t += __shfl_xor(t, 8);
            sm[r] = 1.f / t;
        }
        f32x4 o[2];
        o[0] = {0.f, 0.f, 0.f, 0.f};
        o[1] = {0.f, 0.f, 0.f, 0.f};
        #pragma unroll
        for (int hpp = 0; hpp < 2; ++hpp) {
            #pragma unroll
            for (int mtl = 0; mtl < 4; ++mtl) {
                int mt = hpp * 4 + mtl;
                #pragma unroll
                for (int r = 0; r < 4; ++r)
                    *(__bf16*)(pbase + pswz(lg * 4 + r, (mtl * 16 + l16) * 2)) =
                        (__bf16)(s[mt][r] * sm[r]);
            }
            #pragma unroll
            for (int q = 0; q < 2; ++q) {
                int kc = hpp * 2 + q;
                bf16x8 pafr = *(const bf16x8*)(pbase + pswz(l16, (q * 32 + lg * 8) * 2));
                #pragma unroll
                for (int dt = 0; dt < 2; ++dt)
                    o[dt] = __builtin_amdgcn_mfma_f32_16x16x32_bf16(
                                pafr, vfr[dt][kc], o[dt], 0, 0, 0);
            }
        }
        // O -> global intermediate [b][n][c], c = global head*32 + dt*16 + l16
        #pragma unroll
        for (int dt = 0; dt < 2; ++dt)
            #pragma unroll
            for (int r = 0; r < 4; ++r)
                Og[((size_t)b * 128 + nt * 16 + lg * 4 + r) * 128 +
                   hgl * 32 + dt * 16 + l16] = (__bf16)o[dt][r];
    }
}

// ================= proj kernel: out = O @ W_p^T + b ======================
__global__ void __launch_bounds__(256)
proj_out(const __bf16* __restrict__ Og, const __bf16* __restrict__ wp,
         const float* __restrict__ proj_b, float* __restrict__ out) {
    const int b    = blockIdx.x;
    const int tid  = threadIdx.x;
    const int wave = tid >> 6;
    const int l16  = tid & 15;
    const int lg   = (tid & 63) >> 4;

    f32x4 facc[2][8];
    #pragma unroll
    for (int nt2 = 0; nt2 < 2; ++nt2)
        #pragma unroll
        for (int ct = 0; ct < 8; ++ct)
            facc[nt2][ct] = {0.f, 0.f, 0.f, 0.f};
    #pragma unroll
    for (int kc = 0; kc < 4; ++kc) {
        bf16x8 afr[2];
        #pragma unroll
        for (int nt2 = 0; nt2 < 2; ++nt2)
            afr[nt2] = *(const bf16x8*)(Og +
                          ((size_t)b * 128 + wave * 32 + nt2 * 16 + l16) * 128 +
                          kc * 32 + lg * 8);
        bf16x8 bfr[8];
        #pragma unroll
        for (int ct = 0; ct < 8; ++ct)
            bfr[ct] = *(const bf16x8*)(wp + (ct * 16 + l16) * 128 + kc * 32 + lg * 8);
        #pragma unroll
        for (int nt2 = 0; nt2 < 2; ++nt2)
            #pragma unroll
            for (int ct = 0; ct < 8; ++ct)
                facc[nt2][ct] = __builtin_amdgcn_mfma_f32_16x16x32_bf16(
                                    afr[nt2], bfr[ct], facc[nt2][ct], 0, 0, 0);
    }
    float* ob = out + (size_t)b * 16384;
    #pragma unroll
    for (int ct = 0; ct < 8; ++ct) {
        float pb = proj_b[ct * 16 + l16];
        #pragma unroll
        for (int nt2 = 0; nt2 < 2; ++nt2) {
            int n0 = wave * 32 + nt2 * 16 + lg * 4;
            #pragma unroll
            for (int r = 0; r < 4; ++r)
                ob[(n0 + r) * 128 + ct * 16 + l16] = facc[nt2][ct][r] + pb;
        }
    }
}

// ============== fallback: round-4 monolithic kernel (verified) ===========
#define LDS_XO 0
#define LDS_Q  32768
#define LDS_K  65536
#define LDS_VT 98304
#define LDS_P  131072
#define LDS_TOTAL 147456

__global__ void __launch_bounds__(512, 2)
attn_fused(const float* __restrict__ x, const float* __restrict__ mask,
           const float* __restrict__ qkv_b, const float* __restrict__ proj_b,
           const __bf16* __restrict__ wq, const __bf16* __restrict__ wp,
           float* __restrict__ out) {
    extern __shared__ char smem[];
    const int b    = blockIdx.x;
    const int tid  = threadIdx.x;
    const int wave = tid >> 6;
    const int lane = tid & 63;
    const int l16  = lane & 15;
    const int lg   = lane >> 4;

    {
        const float* xb = x + (size_t)b * 16384;
        #pragma unroll
        for (int it = 0; it < 4; ++it) {
            int i   = it * 512 + tid;
            int row = i >> 4;
            int c8  = (i & 15) << 3;
            float4 f0 = *(const float4*)(xb + row * 128 + c8);
            float4 f1 = *(const float4*)(xb + row * 128 + c8 + 4);
            bf16x8 v;
            v[0] = (__bf16)f0.x; v[1] = (__bf16)f0.y; v[2] = (__bf16)f0.z; v[3] = (__bf16)f0.w;
            v[4] = (__bf16)f1.x; v[5] = (__bf16)f1.y; v[6] = (__bf16)f1.z; v[7] = (__bf16)f1.w;
            *(bf16x8*)(smem + LDS_XO + swz(row, c8 * 2)) = v;
        }
    }
    __syncthreads();

    const int j0 = wave * 48;
    #pragma unroll
    for (int pass = 0; pass < 2; ++pass) {
        f32x4 acc[3][4];
        #pragma unroll
        for (int jt = 0; jt < 3; ++jt)
            #pragma unroll
            for (int nt = 0; nt < 4; ++nt)
                acc[jt][nt] = {0.f, 0.f, 0.f, 0.f};
        #pragma unroll
        for (int kc = 0; kc < 4; ++kc) {
            bf16x8 afr[3];
            #pragma unroll
            for (int jt = 0; jt < 3; ++jt)
                afr[jt] = *(const bf16x8*)(wq + (j0 + jt * 16 + l16) * 128 + kc * 32 + lg * 8);
            bf16x8 bfr[4];
            #pragma unroll
            for (int nt = 0; nt < 4; ++nt)
                bfr[nt] = *(const bf16x8*)(smem + LDS_XO +
                            swz((pass * 4 + nt) * 16 + l16, (kc * 32 + lg * 8) * 2));
            #pragma unroll
            for (int jt = 0; jt < 3; ++jt)
                #pragma unroll
                for (int nt = 0; nt < 4; ++nt)
                    acc[jt][nt] = __builtin_amdgcn_mfma_f32_16x16x32_bf16(
                                      afr[jt], bfr[nt], acc[jt][nt], 0, 0, 0);
        }
        #pragma unroll
        for (int jt = 0; jt < 3; ++jt) {
            int jbase = j0 + jt * 16 + lg * 4;
            float4 bias = *(const float4*)(qkv_b + jbase);
            #pragma unroll
            for (int nt = 0; nt < 4; ++nt) {
                int n = (pass * 4 + nt) * 16 + l16;
                f32x4 a = acc[jt][nt];
                __bf16 e0 = (__bf16)(a[0] + bias.x);
                __bf16 e1 = (__bf16)(a[1] + bias.y);
                __bf16 e2 = (__bf16)(a[2] + bias.z);
                __bf16 e3 = (__bf16)(a[3] + bias.w);
                if (jbase < 128) {
                    bf16x4 v4 = {e0, e1, e2, e3};
                    *(bf16x4*)(smem + LDS_Q + swz(n, jbase * 2)) = v4;
                } else if (jbase < 256) {
                    bf16x4 v4 = {e0, e1, e2, e3};
                    *(bf16x4*)(smem + LDS_K + swz(n, (jbase - 128) * 2)) = v4;
                } else {
                    int d = jbase - 256;
                    *(__bf16*)(smem + LDS_VT + swz(d + 0, n * 2)) = e0;
                    *(__bf16*)(smem + LDS_VT + swz(d + 1, n * 2)) = e1;
                    *(__bf16*)(smem + LDS_VT + swz(d + 2, n * 2)) = e2;
                    *(__bf16*)(smem + LDS_VT + swz(d + 3, n * 2)) = e3;
                }
            }
        }
    }
    __syncthreads();

    const int h  = wave >> 1;
    const int rh = wave & 1;
    const float sc = 0.17677669529663687f;
    bf16x8 kfr[8];
    #pragma unroll
    for (int mt = 0; mt < 8; ++mt)
        kfr[mt] = *(const bf16x8*)(smem + LDS_K + swz(mt * 16 + l16, (h * 32 + lg * 8) * 2));
    bf16x8 vfr[2][4];
    #pragma unroll
    for (int dt = 0; dt < 2; ++dt)
        #pragma unroll
        for (int kc = 0; kc < 4; ++kc)
            vfr[dt][kc] = *(const bf16x8*)(smem + LDS_VT +
                            swz(h * 32 + dt * 16 + l16, (kc * 32 + lg * 8) * 2));

    const float* mwin = mask + (size_t)(b & 63) * 16384;
    char* pbase = smem + LDS_P + wave * 2048;

    #pragma unroll
    for (int i = 0; i < 4; ++i) {
        const int nt = rh * 4 + i;
        bf16x8 qfr = *(const bf16x8*)(smem + LDS_Q + swz(nt * 16 + l16, (h * 32 + lg * 8) * 2));
        f32x4 s[8];
        #pragma unroll
        for (int mt = 0; mt < 8; ++mt) {
            f32x4 z = {0.f, 0.f, 0.f, 0.f};
            s[mt] = __builtin_amdgcn_mfma_f32_16x16x32_bf16(qfr, kfr[mt], z, 0, 0, 0);
        }
        float mx[4] = {-1e30f, -1e30f, -1e30f, -1e30f};
        #pragma unroll
        for (int mt = 0; mt < 8; ++mt)
            #pragma unroll
            for (int r = 0; r < 4; ++r) {
                float v = s[mt][r] * sc + mwin[(nt * 16 + lg * 4 + r) * 128 + mt * 16 + l16];
                s[mt][r] = v;
                mx[r] = fmaxf(mx[r], v);
            }
        #pragma unroll
        for (int r = 0; r < 4; ++r) {
            float m = mx[r];
            m = fmaxf(m, __shfl_xor(m, 1));
            m = fmaxf(m, __shfl_xor(m, 2));
            m = fmaxf(m, __shfl_xor(m, 4));
            m = fmaxf(m, __shfl_xor(m, 8));
            mx[r] = m;
        }
        float sm[4] = {0.f, 0.f, 0.f, 0.f};
        #pragma unroll
        for (int mt = 0; mt < 8; ++mt)
            #pragma unroll
            for (int r = 0; r < 4; ++r) {
                float p = __expf(s[mt][r] - mx[r]);
                s[mt][r] = p;
                sm[r] += p;
            }
        #pragma unroll
        for (int r = 0; r < 4; ++r) {
            float t = sm[r];
            t += __shfl_xor(t, 1);
            t += __shfl_xor(t, 2);
            t += __shfl_xor(t, 4);
            t += __shfl_xor(t, 8);
            sm[r] = 1.f / t;
        }
        f32x4 o[2];
        o[0] = {0.f, 0.f, 0.f, 0.f};
        o[1] = {0.f, 0.f, 0.f, 0.f};
        #pragma unroll
        for (int hp2 = 0; hp2 < 2; ++hp2) {
            #pragma unroll
            for (int mtl = 0; mtl < 4; ++mtl) {
                int mt = hp2 * 4 + mtl;
                #pragma unroll
                for (int r = 0; r < 4; ++r)
                    *(__bf16*)(pbase + pswz(lg * 4 + r, (mtl * 16 + l16) * 2)) =
                        (__bf16)(s[mt][r] * sm[r]);
            }
            #pragma unroll
            for (int q = 0; q < 2; ++q) {
                int kc = hp2 * 2 + q;
                bf16x8 pafr = *(const bf16x8*)(pbase + pswz(l16, (q * 32 + lg * 8) * 2));
                #pragma unroll
                for (int dt = 0; dt < 2; ++dt)
                    o[dt] = __builtin_amdgcn_mfma_f32_16x16x32_bf16(
                                pafr, vfr[dt][kc], o[dt], 0, 0, 0);
            }
        }
        #pragma unroll
        for (int dt = 0; dt < 2; ++dt)
            #pragma unroll
            for (int r = 0; r < 4; ++r)
                *(__bf16*)(smem + LDS_XO +
                    swz(nt * 16 + lg * 4 + r, (h * 32 + dt * 16 + l16) * 2)) = (__bf16)o[dt][r];
    }
    __syncthreads();

    f32x4 facc[8];
    #pragma unroll
    for (int ct = 0; ct < 8; ++ct)
        facc[ct] = {0.f, 0.f, 0.f, 0.f};
    #pragma unroll
    for (int kc = 0; kc < 4; ++kc) {
        bf16x8 afr = *(const bf16x8*)(smem + LDS_XO +
                        swz(wave * 16 + l16, (kc * 32 + lg * 8) * 2));
        bf16x8 bfr[8];
        #pragma unroll
        for (int ct = 0; ct < 8; ++ct)
            bfr[ct] = *(const bf16x8*)(wp + (ct * 16 + l16) * 128 + kc * 32 + lg * 8);
        #pragma unroll
        for (int ct = 0; ct < 8; ++ct)
            facc[ct] = __builtin_amdgcn_mfma_f32_16x16x32_bf16(
                           afr, bfr[ct], facc[ct], 0, 0, 0);
    }
    float* ob = out + (size_t)b * 16384;
    #pragma unroll
    for (int ct = 0; ct < 8; ++ct) {
        float pb = proj_b[ct * 16 + l16];
        int n0 = wave * 16 + lg * 4;
        #pragma unroll
        for (int r = 0; r < 4; ++r)
            ob[(n0 + r) * 128 + ct * 16 + l16] = facc[ct][r] + pb;
    }
}

extern "C" void kernel_launch(void* const* d_in, const int* in_sizes, int n_in,
                              void* d_out, int out_size, void* d_ws, size_t ws_size,
                              hipStream_t stream) {
    const float* x      = (const float*)d_in[0];
    const float* mask   = (const float*)d_in[1];
    const float* qkv_w  = (const float*)d_in[2];
    const float* qkv_b  = (const float*)d_in[3];
    const float* proj_w = (const float*)d_in[4];
    const float* proj_b = (const float*)d_in[5];
    float* out = (float*)d_out;

    __bf16* wq = (__bf16*)d_ws;                       // 384*128 bf16 = 96KB
    __bf16* wp = wq + 49152;                          // 128*128 bf16 = 32KB

    prep_weights<<<192, 256, 0, stream>>>(qkv_w, proj_w, wq, wp);

    const size_t og_bytes = (size_t)2048 * 128 * 128 * 2;
    const size_t need = 131072 + og_bytes;

    if (ws_size >= need) {
        __bf16* Og = (__bf16*)((char*)d_ws + 131072);
        hipFuncSetAttribute((const void*)attn_split,
                            hipFuncAttributeMaxDynamicSharedMemorySize, A_LDS_TOTAL);
        attn_split<<<4096, 256, A_LDS_TOTAL, stream>>>(x, mask, qkv_b, wq, Og);
        proj_out<<<2048, 256, 0, stream>>>(Og, wp, proj_b, out);
    } else {
        hipFuncSetAttribute((const void*)attn_fused,
                            hipFuncAttributeMaxDynamicSharedMemorySize, LDS_TOTAL);
        attn_fused<<<2048, 512, LDS_TOTAL, stream>>>(x, mask, qkv_b, proj_b, wq, wp, out);
    }
}

// Round 6
// 406.866 us; speedup vs baseline: 1.1647x; 1.0039x over previous
//
#include <hip/hip_runtime.h>

typedef __bf16 bf16x8 __attribute__((ext_vector_type(8)));
typedef __bf16 bf16x4 __attribute__((ext_vector_type(4)));
typedef float  f32x4  __attribute__((ext_vector_type(4)));

// XOR swizzle for 256B-row tiles.
__device__ __forceinline__ int swz(int row, int colb) {
    return row * 256 + (colb ^ ((row & 7) << 4));
}
// XOR swizzle for 128B-row tiles.
__device__ __forceinline__ int pswz(int row, int colb) {
    return row * 128 + (colb ^ ((row & 7) << 4));
}

__global__ void prep_weights(const float* __restrict__ qkv_w,
                             const float* __restrict__ proj_w,
                             __bf16* __restrict__ wq, __bf16* __restrict__ wp) {
    int i = blockIdx.x * 256 + threadIdx.x;           // grid covers 49152
    wq[i] = (__bf16)qkv_w[i];
    if (i < 16384) wp[i] = (__bf16)proj_w[i];
}

// ================= split path: (window, head-pair) blocks =================
// LDS = 81920 B exactly -> 2 independent blocks per CU.
#define A_LDS_X   0        // x [128][128] bf16, 256B rows -- dead after Phase B
#define A_LDS_P   0        // P: 4 waves x 4KB, overlays x in Phase C
#define A_LDS_Q   32768    // q [128n][64j] bf16, 128B rows
#define A_LDS_K   49152    // k [128m][64j] bf16, 128B rows
#define A_LDS_VT  65536    // vT [64d][128m] bf16, 256B rows
#define A_LDS_TOTAL 81920

__global__ void __launch_bounds__(256, 2)
attn_split(const float* __restrict__ x, const float* __restrict__ mask,
           const float* __restrict__ qkv_b,
           const __bf16* __restrict__ wq,
           __bf16* __restrict__ Og) {
    extern __shared__ char smem[];
    const int b    = blockIdx.x >> 1;   // window
    const int hp   = blockIdx.x & 1;    // head pair: heads {2hp, 2hp+1}
    const int tid  = threadIdx.x;
    const int wave = tid >> 6;          // 0..3
    const int lane = tid & 63;
    const int l16  = lane & 15;
    const int lg   = lane >> 4;         // 0..3

    // ---------------- Phase A: x -> bf16 LDS (swizzled) ----------------
    {
        const float* xb = x + (size_t)b * 16384;
        #pragma unroll
        for (int it = 0; it < 8; ++it) {
            int i   = it * 256 + tid;
            int row = i >> 4;
            int c8  = (i & 15) << 3;
            float4 f0 = *(const float4*)(xb + row * 128 + c8);
            float4 f1 = *(const float4*)(xb + row * 128 + c8 + 4);
            bf16x8 v;
            v[0] = (__bf16)f0.x; v[1] = (__bf16)f0.y; v[2] = (__bf16)f0.z; v[3] = (__bf16)f0.w;
            v[4] = (__bf16)f1.x; v[5] = (__bf16)f1.y; v[6] = (__bf16)f1.z; v[7] = (__bf16)f1.w;
            *(bf16x8*)(smem + A_LDS_X + swz(row, c8 * 2)) = v;
        }
    }
    __syncthreads();

    // ------- Phase B: this head-pair's qkv features = W @ x^T ----------
    const int f0 = wave * 48;
    #pragma unroll
    for (int pass = 0; pass < 2; ++pass) {
        f32x4 acc[3][4];
        #pragma unroll
        for (int jt = 0; jt < 3; ++jt)
            #pragma unroll
            for (int nt = 0; nt < 4; ++nt)
                acc[jt][nt] = {0.f, 0.f, 0.f, 0.f};
        int jg_t[3];
        #pragma unroll
        for (int jt = 0; jt < 3; ++jt) {
            int ft = f0 + jt * 16;
            jg_t[jt] = (ft < 64) ? (hp * 64 + ft)
                     : (ft < 128) ? (128 + hp * 64 + (ft - 64))
                                  : (256 + hp * 64 + (ft - 128));
        }
        #pragma unroll
        for (int kc = 0; kc < 4; ++kc) {
            bf16x8 afr[3];
            #pragma unroll
            for (int jt = 0; jt < 3; ++jt)
                afr[jt] = *(const bf16x8*)(wq + (jg_t[jt] + l16) * 128 + kc * 32 + lg * 8);
            bf16x8 bfr[4];
            #pragma unroll
            for (int nt = 0; nt < 4; ++nt)
                bfr[nt] = *(const bf16x8*)(smem + A_LDS_X +
                            swz((pass * 4 + nt) * 16 + l16, (kc * 32 + lg * 8) * 2));
            #pragma unroll
            for (int jt = 0; jt < 3; ++jt)
                #pragma unroll
                for (int nt = 0; nt < 4; ++nt)
                    acc[jt][nt] = __builtin_amdgcn_mfma_f32_16x16x32_bf16(
                                      afr[jt], bfr[nt], acc[jt][nt], 0, 0, 0);
        }
        #pragma unroll
        for (int jt = 0; jt < 3; ++jt) {
            int ft = f0 + jt * 16;
            int f  = ft + lg * 4;                 // lane's 4 local features
            float4 bias = *(const float4*)(qkv_b + jg_t[jt] + lg * 4);
            #pragma unroll
            for (int nt = 0; nt < 4; ++nt) {
                int n = (pass * 4 + nt) * 16 + l16;
                f32x4 a = acc[jt][nt];
                __bf16 e0 = (__bf16)(a[0] + bias.x);
                __bf16 e1 = (__bf16)(a[1] + bias.y);
                __bf16 e2 = (__bf16)(a[2] + bias.z);
                __bf16 e3 = (__bf16)(a[3] + bias.w);
                if (f < 64) {
                    bf16x4 v4 = {e0, e1, e2, e3};
                    *(bf16x4*)(smem + A_LDS_Q + pswz(n, f * 2)) = v4;
                } else if (f < 128) {
                    bf16x4 v4 = {e0, e1, e2, e3};
                    *(bf16x4*)(smem + A_LDS_K + pswz(n, (f - 64) * 2)) = v4;
                } else {
                    int d = f - 128;
                    *(__bf16*)(smem + A_LDS_VT + swz(d + 0, n * 2)) = e0;
                    *(__bf16*)(smem + A_LDS_VT + swz(d + 1, n * 2)) = e1;
                    *(__bf16*)(smem + A_LDS_VT + swz(d + 2, n * 2)) = e2;
                    *(__bf16*)(smem + A_LDS_VT + swz(d + 3, n * 2)) = e3;
                }
            }
        }
    }
    __syncthreads();   // x now dead; P buffers overlay it

    // ------- Phase C (swapped-operand): S^T = K @ Q^T ------------------
    // s = mfma(kfr, qfr): lane l16 = q-row, reg (mt, lg*4+r) = k-index.
    const int hl = wave >> 1;           // local head 0/1
    const int rh = wave & 1;
    const int hgl = hp * 2 + hl;        // global head 0..3
    const float sc = 0.17677669529663687f;   // 1/sqrt(32)
    bf16x8 kfr[8];
    #pragma unroll
    for (int mt = 0; mt < 8; ++mt)
        kfr[mt] = *(const bf16x8*)(smem + A_LDS_K +
                      pswz(mt * 16 + l16, (hl * 32 + lg * 8) * 2));
    bf16x8 vfr[2][4];
    #pragma unroll
    for (int dt = 0; dt < 2; ++dt)
        #pragma unroll
        for (int kc = 0; kc < 4; ++kc)
            vfr[dt][kc] = *(const bf16x8*)(smem + A_LDS_VT +
                            swz(hl * 32 + dt * 16 + l16, (kc * 32 + lg * 8) * 2));

    const float* mwin = mask + (size_t)(b & 63) * 16384;
    char* pbase = smem + A_LDS_P + wave * 4096;   // 16 q-rows x 256B

    #pragma unroll
    for (int i = 0; i < 4; ++i) {
        const int nt = rh * 4 + i;
        bf16x8 qfr = *(const bf16x8*)(smem + A_LDS_Q +
                        pswz(nt * 16 + l16, (hl * 32 + lg * 8) * 2));
        f32x4 s[8];
        #pragma unroll
        for (int mt = 0; mt < 8; ++mt) {
            f32x4 z = {0.f, 0.f, 0.f, 0.f};
            s[mt] = __builtin_amdgcn_mfma_f32_16x16x32_bf16(kfr[mt], qfr, z, 0, 0, 0);
        }
        // scale + mask (float4 loads: contiguous k per lane)
        const float* mrow = mwin + (size_t)(nt * 16 + l16) * 128;
        #pragma unroll
        for (int mt = 0; mt < 8; ++mt) {
            float4 mk = *(const float4*)(mrow + mt * 16 + lg * 4);
            s[mt][0] = fmaf(s[mt][0], sc, mk.x);
            s[mt][1] = fmaf(s[mt][1], sc, mk.y);
            s[mt][2] = fmaf(s[mt][2], sc, mk.z);
            s[mt][3] = fmaf(s[mt][3], sc, mk.w);
        }
        // row max: in-register tree + 2 shfls
        f32x4 vm0 = s[0], vm1 = s[1];
        #pragma unroll
        for (int mt = 2; mt < 8; mt += 2) { 
            vm0[0]=fmaxf(vm0[0],s[mt][0]); vm0[1]=fmaxf(vm0[1],s[mt][1]);
            vm0[2]=fmaxf(vm0[2],s[mt][2]); vm0[3]=fmaxf(vm0[3],s[mt][3]);
            vm1[0]=fmaxf(vm1[0],s[mt+1][0]); vm1[1]=fmaxf(vm1[1],s[mt+1][1]);
            vm1[2]=fmaxf(vm1[2],s[mt+1][2]); vm1[3]=fmaxf(vm1[3],s[mt+1][3]);
        }
        float mx = fmaxf(fmaxf(fmaxf(vm0[0],vm1[0]), fmaxf(vm0[1],vm1[1])),
                         fmaxf(fmaxf(vm0[2],vm1[2]), fmaxf(vm0[3],vm1[3])));
        mx = fmaxf(mx, __shfl_xor(mx, 16));
        mx = fmaxf(mx, __shfl_xor(mx, 32));
        // exp (unnormalized P) + row sum
        f32x4 vs = {0.f, 0.f, 0.f, 0.f};
        #pragma unroll
        for (int mt = 0; mt < 8; ++mt) {
            #pragma unroll
            for (int r = 0; r < 4; ++r) {
                float p = __expf(s[mt][r] - mx);
                s[mt][r] = p;
                vs[r] += p;
            }
        }
        float sm = (vs[0] + vs[1]) + (vs[2] + vs[3]);
        sm += __shfl_xor(sm, 16);
        sm += __shfl_xor(sm, 32);
        float inv = 1.f / sm;
        // P -> LDS, vectorized: row q=l16, cols k contiguous
        #pragma unroll
        for (int mt = 0; mt < 8; ++mt) {
            bf16x4 pv = {(__bf16)s[mt][0], (__bf16)s[mt][1],
                         (__bf16)s[mt][2], (__bf16)s[mt][3]};
            *(bf16x4*)(pbase + swz(l16, mt * 32 + lg * 8)) = pv;
        }
        // PV swapped: O^T = V^T @ P^T; lane l16 = q, reg = d
        bf16x8 pafr[4];
        #pragma unroll
        for (int kc = 0; kc < 4; ++kc)
            pafr[kc] = *(const bf16x8*)(pbase + swz(l16, kc * 64 + lg * 16));
        f32x4 o[2];
        o[0] = {0.f, 0.f, 0.f, 0.f};
        o[1] = {0.f, 0.f, 0.f, 0.f};
        #pragma unroll
        for (int kc = 0; kc < 4; ++kc) {
            o[0] = __builtin_amdgcn_mfma_f32_16x16x32_bf16(vfr[0][kc], pafr[kc], o[0], 0, 0, 0);
            o[1] = __builtin_amdgcn_mfma_f32_16x16x32_bf16(vfr[1][kc], pafr[kc], o[1], 0, 0, 0);
        }
        // scale by 1/sum (uniform per lane) + vectorized Og store
        __bf16* og = Og + ((size_t)b * 128 + nt * 16 + l16) * 128 + hgl * 32 + lg * 4;
        #pragma unroll
        for (int dt = 0; dt < 2; ++dt) {
            bf16x4 ov = {(__bf16)(o[dt][0] * inv), (__bf16)(o[dt][1] * inv),
                         (__bf16)(o[dt][2] * inv), (__bf16)(o[dt][3] * inv)};
            *(bf16x4*)(og + dt * 16) = ov;
        }
    }
}

// ================= proj kernel: out = O @ W_p^T + b ======================
// Swapped: mfma(Wp, O) -> D[c][n]: lane l16 = token, reg = c -> float4 stores.
__global__ void __launch_bounds__(256)
proj_out(const __bf16* __restrict__ Og, const __bf16* __restrict__ wp,
         const float* __restrict__ proj_b, float* __restrict__ out) {
    const int b    = blockIdx.x;
    const int tid  = threadIdx.x;
    const int wave = tid >> 6;
    const int l16  = tid & 15;
    const int lg   = (tid & 63) >> 4;

    f32x4 facc[2][8];
    #pragma unroll
    for (int nt2 = 0; nt2 < 2; ++nt2)
        #pragma unroll
        for (int ct = 0; ct < 8; ++ct)
            facc[nt2][ct] = {0.f, 0.f, 0.f, 0.f};
    #pragma unroll
    for (int kc = 0; kc < 4; ++kc) {
        bf16x8 ofr[2];
        #pragma unroll
        for (int nt2 = 0; nt2 < 2; ++nt2)
            ofr[nt2] = *(const bf16x8*)(Og +
                          ((size_t)b * 128 + wave * 32 + nt2 * 16 + l16) * 128 +
                          kc * 32 + lg * 8);
        bf16x8 wfr[8];
        #pragma unroll
        for (int ct = 0; ct < 8; ++ct)
            wfr[ct] = *(const bf16x8*)(wp + (ct * 16 + l16) * 128 + kc * 32 + lg * 8);
        #pragma unroll
        for (int nt2 = 0; nt2 < 2; ++nt2)
            #pragma unroll
            for (int ct = 0; ct < 8; ++ct)
                facc[nt2][ct] = __builtin_amdgcn_mfma_f32_16x16x32_bf16(
                                    wfr[ct], ofr[nt2], facc[nt2][ct], 0, 0, 0);
    }
    float* ob = out + (size_t)b * 16384;
    #pragma unroll
    for (int ct = 0; ct < 8; ++ct) {
        float4 pb4 = *(const float4*)(proj_b + ct * 16 + lg * 4);
        #pragma unroll
        for (int nt2 = 0; nt2 < 2; ++nt2) {
            int n = wave * 32 + nt2 * 16 + l16;
            float4 ov;
            ov.x = facc[nt2][ct][0] + pb4.x;
            ov.y = facc[nt2][ct][1] + pb4.y;
            ov.z = facc[nt2][ct][2] + pb4.z;
            ov.w = facc[nt2][ct][3] + pb4.w;
            *(float4*)(ob + n * 128 + ct * 16 + lg * 4) = ov;
        }
    }
}

// ============== fallback: round-4 monolithic kernel (verified) ===========
#define LDS_XO 0
#define LDS_Q  32768
#define LDS_K  65536
#define LDS_VT 98304
#define LDS_P  131072
#define LDS_TOTAL 147456

__global__ void __launch_bounds__(512, 2)
attn_fused(const float* __restrict__ x, const float* __restrict__ mask,
           const float* __restrict__ qkv_b, const float* __restrict__ proj_b,
           const __bf16* __restrict__ wq, const __bf16* __restrict__ wp,
           float* __restrict__ out) {
    extern __shared__ char smem[];
    const int b    = blockIdx.x;
    const int tid  = threadIdx.x;
    const int wave = tid >> 6;
    const int lane = tid & 63;
    const int l16  = lane & 15;
    const int lg   = lane >> 4;

    {
        const float* xb = x + (size_t)b * 16384;
        #pragma unroll
        for (int it = 0; it < 4; ++it) {
            int i   = it * 512 + tid;
            int row = i >> 4;
            int c8  = (i & 15) << 3;
            float4 f0 = *(const float4*)(xb + row * 128 + c8);
            float4 f1 = *(const float4*)(xb + row * 128 + c8 + 4);
            bf16x8 v;
            v[0] = (__bf16)f0.x; v[1] = (__bf16)f0.y; v[2] = (__bf16)f0.z; v[3] = (__bf16)f0.w;
            v[4] = (__bf16)f1.x; v[5] = (__bf16)f1.y; v[6] = (__bf16)f1.z; v[7] = (__bf16)f1.w;
            *(bf16x8*)(smem + LDS_XO + swz(row, c8 * 2)) = v;
        }
    }
    __syncthreads();

    const int j0 = wave * 48;
    #pragma unroll
    for (int pass = 0; pass < 2; ++pass) {
        f32x4 acc[3][4];
        #pragma unroll
        for (int jt = 0; jt < 3; ++jt)
            #pragma unroll
            for (int nt = 0; nt < 4; ++nt)
                acc[jt][nt] = {0.f, 0.f, 0.f, 0.f};
        #pragma unroll
        for (int kc = 0; kc < 4; ++kc) {
            bf16x8 afr[3];
            #pragma unroll
            for (int jt = 0; jt < 3; ++jt)
                afr[jt] = *(const bf16x8*)(wq + (j0 + jt * 16 + l16) * 128 + kc * 32 + lg * 8);
            bf16x8 bfr[4];
            #pragma unroll
            for (int nt = 0; nt < 4; ++nt)
                bfr[nt] = *(const bf16x8*)(smem + LDS_XO +
                            swz((pass * 4 + nt) * 16 + l16, (kc * 32 + lg * 8) * 2));
            #pragma unroll
            for (int jt = 0; jt < 3; ++jt)
                #pragma unroll
                for (int nt = 0; nt < 4; ++nt)
                    acc[jt][nt] = __builtin_amdgcn_mfma_f32_16x16x32_bf16(
                                      afr[jt], bfr[nt], acc[jt][nt], 0, 0, 0);
        }
        #pragma unroll
        for (int jt = 0; jt < 3; ++jt) {
            int jbase = j0 + jt * 16 + lg * 4;
            float4 bias = *(const float4*)(qkv_b + jbase);
            #pragma unroll
            for (int nt = 0; nt < 4; ++nt) {
                int n = (pass * 4 + nt) * 16 + l16;
                f32x4 a = acc[jt][nt];
                __bf16 e0 = (__bf16)(a[0] + bias.x);
                __bf16 e1 = (__bf16)(a[1] + bias.y);
                __bf16 e2 = (__bf16)(a[2] + bias.z);
                __bf16 e3 = (__bf16)(a[3] + bias.w);
                if (jbase < 128) {
                    bf16x4 v4 = {e0, e1, e2, e3};
                    *(bf16x4*)(smem + LDS_Q + swz(n, jbase * 2)) = v4;
                } else if (jbase < 256) {
                    bf16x4 v4 = {e0, e1, e2, e3};
                    *(bf16x4*)(smem + LDS_K + swz(n, (jbase - 128) * 2)) = v4;
                } else {
                    int d = jbase - 256;
                    *(__bf16*)(smem + LDS_VT + swz(d + 0, n * 2)) = e0;
                    *(__bf16*)(smem + LDS_VT + swz(d + 1, n * 2)) = e1;
                    *(__bf16*)(smem + LDS_VT + swz(d + 2, n * 2)) = e2;
                    *(__bf16*)(smem + LDS_VT + swz(d + 3, n * 2)) = e3;
                }
            }
        }
    }
    __syncthreads();

    const int h  = wave >> 1;
    const int rh = wave & 1;
    const float sc = 0.17677669529663687f;
    bf16x8 kfr[8];
    #pragma unroll
    for (int mt = 0; mt < 8; ++mt)
        kfr[mt] = *(const bf16x8*)(smem + LDS_K + swz(mt * 16 + l16, (h * 32 + lg * 8) * 2));
    bf16x8 vfr[2][4];
    #pragma unroll
    for (int dt = 0; dt < 2; ++dt)
        #pragma unroll
        for (int kc = 0; kc < 4; ++kc)
            vfr[dt][kc] = *(const bf16x8*)(smem + LDS_VT +
                            swz(h * 32 + dt * 16 + l16, (kc * 32 + lg * 8) * 2));

    const float* mwin = mask + (size_t)(b & 63) * 16384;
    char* pbase = smem + LDS_P + wave * 2048;

    #pragma unroll
    for (int i = 0; i < 4; ++i) {
        const int nt = rh * 4 + i;
        bf16x8 qfr = *(const bf16x8*)(smem + LDS_Q + swz(nt * 16 + l16, (h * 32 + lg * 8) * 2));
        f32x4 s[8];
        #pragma unroll
        for (int mt = 0; mt < 8; ++mt) {
            f32x4 z = {0.f, 0.f, 0.f, 0.f};
            s[mt] = __builtin_amdgcn_mfma_f32_16x16x32_bf16(qfr, kfr[mt], z, 0, 0, 0);
        }
        float mx[4] = {-1e30f, -1e30f, -1e30f, -1e30f};
        #pragma unroll
        for (int mt = 0; mt < 8; ++mt)
            #pragma unroll
            for (int r = 0; r < 4; ++r) {
                float v = s[mt][r] * sc + mwin[(nt * 16 + lg * 4 + r) * 128 + mt * 16 + l16];
                s[mt][r] = v;
                mx[r] = fmaxf(mx[r], v);
            }
        #pragma unroll
        for (int r = 0; r < 4; ++r) {
            float m = mx[r];
            m = fmaxf(m, __shfl_xor(m, 1));
            m = fmaxf(m, __shfl_xor(m, 2));
            m = fmaxf(m, __shfl_xor(m, 4));
            m = fmaxf(m, __shfl_xor(m, 8));
            mx[r] = m;
        }
        float sm[4] = {0.f, 0.f, 0.f, 0.f};
        #pragma unroll
        for (int mt = 0; mt < 8; ++mt)
            #pragma unroll
            for (int r = 0; r < 4; ++r) {
                float p = __expf(s[mt][r] - mx[r]);
                s[mt][r] = p;
                sm[r] += p;
            }
        #pragma unroll
        for (int r = 0; r < 4; ++r) {
            float t = sm[r];
            t += __shfl_xor(t, 1);
            t += __shfl_xor(t, 2);
            t += __shfl_xor(t, 4);
            t += __shfl_xor(t, 8);
            sm[r] = 1.f / t;
        }
        f32x4 o[2];
        o[0] = {0.f, 0.f, 0.f, 0.f};
        o[1] = {0.f, 0.f, 0.f, 0.f};
        #pragma unroll
        for (int hp2 = 0; hp2 < 2; ++hp2) {
            #pragma unroll
            for (int mtl = 0; mtl < 4; ++mtl) {
                int mt = hp2 * 4 + mtl;
                #pragma unroll
                for (int r = 0; r < 4; ++r)
                    *(__bf16*)(pbase + pswz(lg * 4 + r, (mtl * 16 + l16) * 2)) =
                        (__bf16)(s[mt][r] * sm[r]);
            }
            #pragma unroll
            for (int q = 0; q < 2; ++q) {
                int kc = hp2 * 2 + q;
                bf16x8 pafr = *(const bf16x8*)(pbase + pswz(l16, (q * 32 + lg * 8) * 2));
                #pragma unroll
                for (int dt = 0; dt < 2; ++dt)
                    o[dt] = __builtin_amdgcn_mfma_f32_16x16x32_bf16(
                                pafr, vfr[dt][kc], o[dt], 0, 0, 0);
            }
        }
        #pragma unroll
        for (int dt = 0; dt < 2; ++dt)
            #pragma unroll
            for (int r = 0; r < 4; ++r)
                *(__bf16*)(smem + LDS_XO +
                    swz(nt * 16 + lg * 4 + r, (h * 32 + dt * 16 + l16) * 2)) = (__bf16)o[dt][r];
    }
    __syncthreads();

    f32x4 facc[8];
    #pragma unroll
    for (int ct = 0; ct < 8; ++ct)
        facc[ct] = {0.f, 0.f, 0.f, 0.f};
    #pragma unroll
    for (int kc = 0; kc < 4; ++kc) {
        bf16x8 afr = *(const bf16x8*)(smem + LDS_XO +
                        swz(wave * 16 + l16, (kc * 32 + lg * 8) * 2));
        bf16x8 bfr[8];
        #pragma unroll
        for (int ct = 0; ct < 8; ++ct)
            bfr[ct] = *(const bf16x8*)(wp + (ct * 16 + l16) * 128 + kc * 32 + lg * 8);
        #pragma unroll
        for (int ct = 0; ct < 8; ++ct)
            facc[ct] = __builtin_amdgcn_mfma_f32_16x16x32_bf16(
                           afr, bfr[ct], facc[ct], 0, 0, 0);
    }
    float* ob = out + (size_t)b * 16384;
    #pragma unroll
    for (int ct = 0; ct < 8; ++ct) {
        float pb = proj_b[ct * 16 + l16];
        int n0 = wave * 16 + lg * 4;
        #pragma unroll
        for (int r = 0; r < 4; ++r)
            ob[(n0 + r) * 128 + ct * 16 + l16] = facc[ct][r] + pb;
    }
}

extern "C" void kernel_launch(void* const* d_in, const int* in_sizes, int n_in,
                              void* d_out, int out_size, void* d_ws, size_t ws_size,
                              hipStream_t stream) {
    const float* x      = (const float*)d_in[0];
    const float* mask   = (const float*)d_in[1];
    const float* qkv_w  = (const float*)d_in[2];
    const float* qkv_b  = (const float*)d_in[3];
    const float* proj_w = (const float*)d_in[4];
    const float* proj_b = (const float*)d_in[5];
    float* out = (float*)d_out;

    __bf16* wq = (__bf16*)d_ws;                       // 384*128 bf16 = 96KB
    __bf16* wp = wq + 49152;                          // 128*128 bf16 = 32KB

    prep_weights<<<192, 256, 0, stream>>>(qkv_w, proj_w, wq, wp);

    const size_t og_bytes = (size_t)2048 * 128 * 128 * 2;
    const size_t need = 131072 + og_bytes;

    if (ws_size >= need) {
        __bf16* Og = (__bf16*)((char*)d_ws + 131072);
        hipFuncSetAttribute((const void*)attn_split,
                            hipFuncAttributeMaxDynamicSharedMemorySize, A_LDS_TOTAL);
        attn_split<<<4096, 256, A_LDS_TOTAL, stream>>>(x, mask, qkv_b, wq, Og);
        proj_out<<<2048, 256, 0, stream>>>(Og, wp, proj_b, out);
    } else {
        hipFuncSetAttribute((const void*)attn_fused,
                            hipFuncAttributeMaxDynamicSharedMemorySize, LDS_TOTAL);
        attn_fused<<<2048, 512, LDS_TOTAL, stream>>>(x, mask, qkv_b, proj_b, wq, wp, out);
    }
}